// Round 14
// baseline (568.986 us; speedup 1.0000x reference)
//
#include <hip/hip_runtime.h>
#include <hip/hip_bf16.h>

#define N_NODES 10000
#define E_EDGES 160000
#define ETOT    170000   // E + N self loops
#define H_HEADS 8
#define C_CH    128
#define D_DIM   1024
#define NBLK    3
#define NGRAPH  64
#define NEG_SLOPE 0.2f
#define BN_EPS  1e-5f

typedef __attribute__((ext_vector_type(8))) _Float16 half8;
typedef __attribute__((ext_vector_type(4))) _Float16 half4;
typedef __attribute__((ext_vector_type(2))) _Float16 half2v;
typedef __attribute__((ext_vector_type(4))) float f32x4;

// first index i in sorted batch[0..N) with batch[i] >= g
__device__ inline int lower_bound_batch(const int* __restrict__ batch, int g) {
    int lo = 0, hi = N_NODES;
    while (lo < hi) {
        int mid = (lo + hi) >> 1;
        if (batch[mid] < g) lo = mid + 1;
        else hi = mid;
    }
    return lo;
}

// ---------------- CSR build ----------------
__global__ void deg_kernel(const int* __restrict__ ei, int* __restrict__ deg) {
    int tid = blockIdx.x * blockDim.x + threadIdx.x;
    if (tid >= ETOT) return;
    int dst = (tid < E_EDGES) ? ei[E_EDGES + tid] : (tid - E_EDGES);
    atomicAdd(&deg[dst], 1);
}

__global__ void scan_kernel(const int* __restrict__ deg, int* __restrict__ ioff) {
    __shared__ int part[256];
    int t = threadIdx.x;
    const int CH = (N_NODES + 255) / 256; // 40
    int base = t * CH;
    int s = 0;
    for (int j = 0; j < CH; ++j) {
        int idx = base + j;
        if (idx < N_NODES) s += deg[idx];
    }
    part[t] = s;
    __syncthreads();
    for (int o = 1; o < 256; o <<= 1) {
        int v = 0;
        if (t >= o) v = part[t - o];
        __syncthreads();
        part[t] += v;
        __syncthreads();
    }
    int run = (t == 0) ? 0 : part[t - 1];
    for (int j = 0; j < CH; ++j) {
        int idx = base + j;
        if (idx < N_NODES) { ioff[idx] = run; run += deg[idx]; }
    }
}

__global__ void scatter_kernel(const int* __restrict__ ei, int* __restrict__ ioff,
                               int* __restrict__ csr_src, int* __restrict__ csr_dst) {
    int tid = blockIdx.x * blockDim.x + threadIdx.x;
    if (tid >= ETOT) return;
    int src, dst;
    if (tid < E_EDGES) { src = ei[tid]; dst = ei[E_EDGES + tid]; }
    else { src = dst = tid - E_EDGES; }
    int pos = atomicAdd(&ioff[dst], 1);
    csr_src[pos] = src;
    csr_dst[pos] = dst;
}

// ---------------- x -> fp16 ----------------
__global__ __launch_bounds__(256) void xconv_kernel(const float* __restrict__ in,
                                                    _Float16* __restrict__ o, int n4) {
    int i = blockIdx.x * blockDim.x + threadIdx.x;
    if (i >= n4) return;
    float4 v = ((const float4*)in)[i];
    half4 h = {(_Float16)v.x, (_Float16)v.y, (_Float16)v.z, (_Float16)v.w};
    ((half4*)o)[i] = h;
}

// W [k][n] fp32 -> Wt [n][k] fp16 (transposed); blockIdx.z = layer
__global__ __launch_bounds__(256) void wtconv_kernel(const float* __restrict__ Wall,
                                                     _Float16* __restrict__ t16all) {
    const float* W = Wall + (size_t)blockIdx.z * D_DIM * D_DIM;
    _Float16* t16 = t16all + (size_t)blockIdx.z * D_DIM * D_DIM;
    __shared__ float t[32][33];
    int bn = blockIdx.x * 32;
    int bk = blockIdx.y * 32;
    int tx = threadIdx.x & 31;
    int ty = threadIdx.x >> 5;
#pragma unroll
    for (int r = 0; r < 32; r += 8)
        t[ty + r][tx] = W[(size_t)(bk + ty + r) * D_DIM + bn + tx];
    __syncthreads();
#pragma unroll
    for (int r = 0; r < 32; r += 8)
        t16[(size_t)(bn + ty + r) * D_DIM + bk + tx] = (_Float16)t[tx][ty + r];
}

// ---------------- fp16 MFMA GEMM + fused attention-logit epilogue ----------------
// R9-proven shape: 128x64 tile, 4 waves, acc[2][4] = 32 AGPR -> 4 waves/SIMD,
// grid 79x16 work blocks, occupancy ~36%. The 2-barrier schedule's ~44us is
// this GEMM's structural floor (dbuf x3 regressed via occupancy loss;
// BK-doubling neutral; tile-halving neutral-negative). Att-logit partials via
// atomicAdd into pre-zeroed asrc/adst. R2-proven XOR swizzle.
// XCD map: c=bx&7 owns m-tiles {c,c+8,..}.
__global__ __launch_bounds__(256, 4) void gemm_mfma_kernel(const _Float16* __restrict__ A,
                                                           const _Float16* __restrict__ Bt,
                                                           _Float16* __restrict__ Hout,
                                                           const float* __restrict__ att_s,
                                                           const float* __restrict__ att_d,
                                                           float* __restrict__ asrc,
                                                           float* __restrict__ adst,
                                                           float* __restrict__ stats, int M) {
    __shared__ short As[128 * 64]; // [m][k] fp16 bits, swizzled slots, 16 KB
    __shared__ short Bs[64 * 64];  // [n][k], 8 KB
    int bx = blockIdx.x;
    int tid = threadIdx.x;
    if (bx == 0) {
#pragma unroll
        for (int j = 0; j < 8; ++j) stats[tid + j * 256] = 0.f;
    }
    int c = bx & 7;
    int nt = (bx >> 3) & 15;
    int mt = c + 8 * (bx >> 7);
    if (mt >= 79) return;
    int bm = mt * 128;
    int head = nt >> 1;
    int bncol = (nt & 1) * 64;   // col offset within head's 128 channels
    int bnrow = nt * 64;         // row offset in Bt [1024][1024]
    int wave = tid >> 6;
    int lane = tid & 63;
    int wm = wave * 32;          // wave owns rows wm..wm+31, all 64 cols
    int quad = lane >> 4;
    int l16 = lane & 15;

    f32x4 acc[2][4];
#pragma unroll
    for (int i = 0; i < 2; ++i)
#pragma unroll
        for (int j = 0; j < 4; ++j) acc[i][j] = (f32x4){0.f, 0.f, 0.f, 0.f};

    // staging geometry: 8 lanes/row, 8 x 16B slots per 128B row (BK=64)
    int srow8 = lane >> 3;                       // 0..7
    int sswz = ((lane & 7) ^ srow8) << 4;        // swizzled source slot (bytes)
    const char* gA[4];
    const char* gB[2];
    char* ldA[4];
    char* ldB[2];
#pragma unroll
    for (int r = 0; r < 4; ++r) {
        int arow = wave * 8 + r * 32 + srow8;    // 0..127
        int ga = bm + arow;
        if (ga > M - 1) ga = M - 1;
        gA[r] = (const char*)(A + (size_t)ga * 1024) + sswz;
        ldA[r] = (char*)As + (wave * 8 + r * 32) * 128;  // wave-uniform dest
    }
#pragma unroll
    for (int r = 0; r < 2; ++r) {
        int brow = wave * 8 + r * 32 + srow8;    // 0..63
        gB[r] = (const char*)(Bt + (size_t)(bnrow + brow) * 1024) + sswz;
        ldB[r] = (char*)Bs + (wave * 8 + r * 32) * 128;
    }

    int xr = l16 & 7;   // read-side XOR = row&7
    for (int kb = 0; kb < 16; ++kb) {
        int ko = kb * 128;  // 64 fp16 per row per step
#pragma unroll
        for (int r = 0; r < 4; ++r)
            __builtin_amdgcn_global_load_lds(
                (const __attribute__((address_space(1))) void*)(gA[r] + ko),
                (__attribute__((address_space(3))) void*)ldA[r], 16, 0, 0);
#pragma unroll
        for (int r = 0; r < 2; ++r)
            __builtin_amdgcn_global_load_lds(
                (const __attribute__((address_space(1))) void*)(gB[r] + ko),
                (__attribute__((address_space(3))) void*)ldB[r], 16, 0, 0);
        __syncthreads();
#pragma unroll
        for (int h = 0; h < 2; ++h) {
            int sl = (quad + h * 4) ^ xr;   // swizzled 16B slot to read
            half8 af[2], bfr[4];
#pragma unroll
            for (int i = 0; i < 2; ++i)
                af[i] = *(const half8*)(As + (wm + i * 16 + l16) * 64 + sl * 8);
#pragma unroll
            for (int j = 0; j < 4; ++j)
                bfr[j] = *(const half8*)(Bs + (j * 16 + l16) * 64 + sl * 8);
#pragma unroll
            for (int i = 0; i < 2; ++i)
#pragma unroll
                for (int j = 0; j < 4; ++j)
                    acc[i][j] = __builtin_amdgcn_mfma_f32_16x16x32_f16(af[i], bfr[j], acc[i][j], 0, 0, 0);
        }
        __syncthreads();
    }

    // attention-logit partial dots over this block's 64 cols; full 128-channel
    // dot is completed via atomicAdd across the nt-even/nt-odd block pair.
    float wsv[4], wdv[4];
#pragma unroll
    for (int j = 0; j < 4; ++j) {
        int cc = bncol + j * 16 + l16;
        wsv[j] = att_s[head * 128 + cc];
        wdv[j] = att_d[head * 128 + cc];
    }
#pragma unroll
    for (int i = 0; i < 2; ++i) {
#pragma unroll
        for (int reg = 0; reg < 4; ++reg) {
            float p = acc[i][0][reg] * wsv[0] + acc[i][1][reg] * wsv[1] +
                      acc[i][2][reg] * wsv[2] + acc[i][3][reg] * wsv[3];
            float q = acc[i][0][reg] * wdv[0] + acc[i][1][reg] * wdv[1] +
                      acc[i][2][reg] * wdv[2] + acc[i][3][reg] * wdv[3];
#pragma unroll
            for (int o = 1; o < 16; o <<= 1) {
                p += __shfl_xor(p, o);
                q += __shfl_xor(q, o);
            }
            if (l16 == 0) {
                int gr = bm + wm + i * 16 + quad * 4 + reg;
                if (gr < M) {
                    atomicAdd(&asrc[gr * 8 + head], p);
                    atomicAdd(&adst[gr * 8 + head], q);
                }
            }
        }
    }
    // store h fp16, head-major: Hout[head][row][col128]
#pragma unroll
    for (int i = 0; i < 2; ++i) {
#pragma unroll
        for (int reg = 0; reg < 4; ++reg) {
            int gr = bm + wm + i * 16 + quad * 4 + reg;
            if (gr < M) {
                _Float16* hp = Hout + (size_t)head * N_NODES * 128 + (size_t)gr * 128 + bncol + l16;
#pragma unroll
                for (int j = 0; j < 4; ++j) hp[j * 16] = (_Float16)acc[i][j][reg];
            }
        }
    }
}

// ---------------- per-edge softmax numerator pre-pass ----------------
// One thread per CSR slot, all 8 heads. Hoists exp(leaky(asrc[src]+adst[dst]))
// out of agg's channel-parallel inner loop (R0 lesson; R6's in-loop exp
// regressed). R21: exw is HEAD-MAJOR [8][ETOT] (R7 proven: agg FETCH
// 56.5 -> 28 MB, cross-XCD over-fetch eliminated).
__global__ __launch_bounds__(256) void edge_exp_kernel(const int* __restrict__ csr_src,
                                                       const int* __restrict__ csr_dst,
                                                       const float* __restrict__ asrc,
                                                       const float* __restrict__ adst,
                                                       float* __restrict__ exw) {
    int p = blockIdx.x * 256 + threadIdx.x;
    if (p >= ETOT) return;
    int s = csr_src[p];
    int d = csr_dst[p];
    float4 s0 = *(const float4*)(asrc + (unsigned)s * 8u);
    float4 s1 = *(const float4*)(asrc + (unsigned)s * 8u + 4u);
    float4 d0 = *(const float4*)(adst + (unsigned)d * 8u);
    float4 d1 = *(const float4*)(adst + (unsigned)d * 8u + 4u);
    float e[8] = {s0.x + d0.x, s0.y + d0.y, s0.z + d0.z, s0.w + d0.w,
                  s1.x + d1.x, s1.y + d1.y, s1.z + d1.z, s1.w + d1.w};
#pragma unroll
    for (int j = 0; j < 8; ++j) {
        float v = e[j];
        v = (v > 0.f) ? v : NEG_SLOPE * v;
        exw[j * ETOT + p] = __expf(v);
    }
}

// ---------------- fused edge-softmax aggregation v5 (R23, proven R9) ----------------
// One wave per (node,head): sub = lane>>4 is the edge slot (4 edges per
// gather instruction), l16 = lane&15 covers 128 ch via half8. Single loop
// bound per wave -> zero divergence. shfl_xor(16,32) folds the 4 slots;
// lanes 0-15 (sub==0) write the half8 row. head = bx&7 keeps per-XCD h16
// slice (2.56 MB) L2-resident.
__global__ __launch_bounds__(256) void agg_kernel(const _Float16* __restrict__ h16,
                                                  const float* __restrict__ exw,
                                                  const int* __restrict__ ioff,
                                                  const int* __restrict__ csr_src,
                                                  const _Float16* __restrict__ prevh,
                                                  const float* __restrict__ bias,
                                                  _Float16* __restrict__ yout) {
    int bx = blockIdx.x;
    int head = bx & 7;
    int wave = threadIdx.x >> 6;
    int lane = threadIdx.x & 63;
    int sub = lane >> 4;              // edge slot 0..3
    int l16 = lane & 15;              // channel group (8 ch each)
    unsigned c8 = (unsigned)(l16 * 8);
    int n = (bx >> 3) * 4 + wave;     // N=10000 divisible by 4
    const _Float16* hh = h16 + (size_t)head * N_NODES * 128;
    const float* exh = exw + (size_t)head * ETOT;
    int start = (n == 0) ? 0 : ioff[n - 1];
    int end = ioff[n];
    float den = 0.f;
    float acc[8];
#pragma unroll
    for (int j = 0; j < 8; ++j) acc[j] = 0.f;
    int p = start;
    for (; p + 8 <= end; p += 8) {
        int sA = csr_src[p + sub];
        int sB = csr_src[p + 4 + sub];
        float xA = exh[p + sub];
        float xB = exh[p + 4 + sub];
        half8 hA = *(const half8*)(hh + ((unsigned)sA * 128u + c8));
        half8 hB = *(const half8*)(hh + ((unsigned)sB * 128u + c8));
        den += xA + xB;
#pragma unroll
        for (int j = 0; j < 8; ++j)
            acc[j] = fmaf(xA, (float)hA[j], fmaf(xB, (float)hB[j], acc[j]));
    }
    for (; p + 4 <= end; p += 4) {
        int s = csr_src[p + sub];
        float x = exh[p + sub];
        half8 hv = *(const half8*)(hh + ((unsigned)s * 128u + c8));
        den += x;
#pragma unroll
        for (int j = 0; j < 8; ++j)
            acc[j] = fmaf(x, (float)hv[j], acc[j]);
    }
    if (p + sub < end) {
        int s = csr_src[p + sub];
        float x = exh[p + sub];
        half8 hv = *(const half8*)(hh + ((unsigned)s * 128u + c8));
        den += x;
#pragma unroll
        for (int j = 0; j < 8; ++j)
            acc[j] = fmaf(x, (float)hv[j], acc[j]);
    }
    // fold the 4 edge slots (lanes ^16, ^32)
#pragma unroll
    for (int j = 0; j < 8; ++j) {
        acc[j] += __shfl_xor(acc[j], 16);
        acc[j] += __shfl_xor(acc[j], 32);
    }
    den += __shfl_xor(den, 16);
    den += __shfl_xor(den, 32);
    if (sub == 0) {
        float invd = 1.0f / den;
        int col = head * 128 + l16 * 8;
        half8 ph = *(const half8*)(prevh + (size_t)n * 1024 + col);
        float4 b0 = *(const float4*)(bias + col);
        float4 b1 = *(const float4*)(bias + col + 4);
        half8 o;
        o[0] = (_Float16)fmaf(acc[0], invd, (float)ph[0] + b0.x);
        o[1] = (_Float16)fmaf(acc[1], invd, (float)ph[1] + b0.y);
        o[2] = (_Float16)fmaf(acc[2], invd, (float)ph[2] + b0.z);
        o[3] = (_Float16)fmaf(acc[3], invd, (float)ph[3] + b0.w);
        o[4] = (_Float16)fmaf(acc[4], invd, (float)ph[4] + b1.x);
        o[5] = (_Float16)fmaf(acc[5], invd, (float)ph[5] + b1.y);
        o[6] = (_Float16)fmaf(acc[6], invd, (float)ph[6] + b1.z);
        o[7] = (_Float16)fmaf(acc[7], invd, (float)ph[7] + b1.w);
        *(half8*)(yout + (size_t)n * 1024 + col) = o;
    }
}

// ---------------- batchnorm (fp16 y) ----------------
// R28: half4 loads with NAMED scalar accumulators (R12's failure was float
// ARRAYS demoted to scratch — VGPR 16, 116us; named scalars are the proven
// form). 256 blocks, each covers all 1024 cols (col = tid*4, 512B/wave
// coalesced), rows strided 256 -> 39 iters of 8B loads (was 78 x 4B).
// 524k atomics to 2048 addrs (~256/addr chain ~ 3us). Stats from the same
// fp16-rounded y16 that bn_apply reads (R11 lesson). stats zeroed by gemm
// block 0.
__global__ __launch_bounds__(256) void bn_stats_kernel(const _Float16* __restrict__ y,
                                                       float* __restrict__ stats) {
    int col = threadIdx.x * 4;
    float s0 = 0.f, s1 = 0.f, s2 = 0.f, s3 = 0.f;
    float q0 = 0.f, q1 = 0.f, q2 = 0.f, q3 = 0.f;
    for (int r = blockIdx.x; r < N_NODES; r += 256) {
        half4 v = *(const half4*)(y + (size_t)r * 1024 + col);
        float a = (float)v[0], b = (float)v[1], c = (float)v[2], d = (float)v[3];
        s0 += a; q0 += a * a;
        s1 += b; q1 += b * b;
        s2 += c; q2 += c * c;
        s3 += d; q3 += d * d;
    }
    atomicAdd(&stats[col + 0], s0);
    atomicAdd(&stats[col + 1], s1);
    atomicAdd(&stats[col + 2], s2);
    atomicAdd(&stats[col + 3], s3);
    atomicAdd(&stats[1024 + col + 0], q0);
    atomicAdd(&stats[1024 + col + 1], q1);
    atomicAdd(&stats[1024 + col + 2], q2);
    atomicAdd(&stats[1024 + col + 3], q3);
}

// normalize+relu: y16 -> o16 (o is next layer's GEMM A / prev / pool input).
// half8 (16B/lane, G13). Prefix threads also zero asrc/adst (2*N*H floats)
// for the NEXT layer's gemm atomics (edge_exp of this layer already consumed
// them — stream-ordered).
__global__ __launch_bounds__(256) void bn_apply_kernel(const _Float16* __restrict__ y,
                                                       const float* __restrict__ stats,
                                                       const float* __restrict__ gamma,
                                                       const float* __restrict__ beta,
                                                       _Float16* __restrict__ oout,
                                                       float* __restrict__ azero) {
    int idx8 = blockIdx.x * 256 + threadIdx.x;
    if (idx8 < 2 * N_NODES * H_HEADS / 4)
        ((float4*)azero)[idx8] = make_float4(0.f, 0.f, 0.f, 0.f);
    if (idx8 >= N_NODES * D_DIM / 8) return;
    int col = (idx8 * 8) & 1023;
    const float invN = 1.0f / (float)N_NODES;
    half8 v = ((const half8*)y)[idx8];
    half8 o;
#pragma unroll
    for (int j = 0; j < 8; ++j) {
        int cc = col + j;
        float mu = stats[cc] * invN;
        float var = stats[1024 + cc] * invN - mu * mu;
        float t = ((float)v[j] - mu) * rsqrtf(var + BN_EPS) * gamma[cc] + beta[cc];
        o[j] = (_Float16)fmaxf(t, 0.f);
    }
    ((half8*)oout)[idx8] = o;
}

// ---------------- pooling stage 1: partial col-sums, 512 blocks ----------------
__global__ __launch_bounds__(256) void pool_kernel(const _Float16* __restrict__ h3,
                                                   const int* __restrict__ batch,
                                                   float* __restrict__ pooled) {
    int g = blockIdx.y;
    int col = threadIdx.x * 4;
    int lo = lower_bound_batch(batch, g);
    int hi = lower_bound_batch(batch, g + 1);
    int len = hi - lo;
    int r0 = lo + (int)(((long long)len * blockIdx.x) >> 3);
    int r1 = lo + (int)(((long long)len * (blockIdx.x + 1)) >> 3);
    float a0 = 0.f, a1 = 0.f, a2 = 0.f, a3 = 0.f;
    for (int r = r0; r < r1; ++r) {
        half4 v = *(const half4*)(h3 + (size_t)r * 1024 + col);
        a0 += (float)v[0]; a1 += (float)v[1]; a2 += (float)v[2]; a3 += (float)v[3];
    }
    if (r1 > r0) {
        atomicAdd(&pooled[(size_t)g * 1024 + col + 0], a0);
        atomicAdd(&pooled[(size_t)g * 1024 + col + 1], a1);
        atomicAdd(&pooled[(size_t)g * 1024 + col + 2], a2);
        atomicAdd(&pooled[(size_t)g * 1024 + col + 3], a3);
    }
}

__global__ void final_kernel(const float* __restrict__ pooled, const int* __restrict__ batch,
                             const float* __restrict__ Wout, const float* __restrict__ bout,
                             float* __restrict__ out) {
    int g = blockIdx.x;
    int t = threadIdx.x;
    float p0 = 0.f, p1 = 0.f;
    for (int d = t; d < 1024; d += 256) {
        float v = pooled[(size_t)g * 1024 + d];
        p0 = fmaf(v, Wout[2 * d], p0);
        p1 = fmaf(v, Wout[2 * d + 1], p1);
    }
    __shared__ float s0[256], s1[256];
    s0[t] = p0; s1[t] = p1;
    __syncthreads();
    for (int o = 128; o; o >>= 1) {
        if (t < o) { s0[t] += s0[t + o]; s1[t] += s1[t + o]; }
        __syncthreads();
    }
    if (t == 0) {
        int cnt = lower_bound_batch(batch, g + 1) - lower_bound_batch(batch, g);
        float inv = 1.0f / fmaxf((float)cnt, 1.0f);
        out[g * 2 + 0] = s0[0] * inv + bout[0];
        out[g * 2 + 1] = s1[0] * inv + bout[1];
    }
}

extern "C" void kernel_launch(void* const* d_in, const int* in_sizes, int n_in,
                              void* d_out, int out_size, void* d_ws, size_t ws_size,
                              hipStream_t stream) {
    const float* x        = (const float*)d_in[0];
    const int*   ei       = (const int*)d_in[1];
    const int*   batch    = (const int*)d_in[2];
    const float* W        = (const float*)d_in[3];
    const float* att_src  = (const float*)d_in[4];
    const float* att_dst  = (const float*)d_in[5];
    const float* att_bias = (const float*)d_in[6];
    const float* gamma    = (const float*)d_in[7];
    const float* beta     = (const float*)d_in[8];
    const float* Wout     = (const float*)d_in[9];
    const float* bout     = (const float*)d_in[10];
    float* out = (float*)d_out;

    const size_t ND = (size_t)N_NODES * D_DIM;
    float* ws = (float*)d_ws;
    float* asrc   = ws;                                  // N*H
    float* adst   = asrc + (size_t)N_NODES * H_HEADS;    // N*H (contiguous w/ asrc)
    float* stats  = adst + (size_t)N_NODES * H_HEADS;    // 2*D
    float* pooled = stats + 2 * D_DIM;                   // NG*D
    int* ideg     = (int*)(pooled + (size_t)NGRAPH * D_DIM); // N
    int* ioff     = ideg + N_NODES;                      // N
    int* csr_src  = ioff + N_NODES;                      // ETOT
    int* csr_dst  = csr_src + ETOT;                      // ETOT
    float* exw    = (float*)(csr_dst + ETOT);            // H*ETOT head-major (R21)
    _Float16* bufP  = (_Float16*)(exw + (size_t)ETOT * H_HEADS); // N*D: x16 -> o1 -> o2
    _Float16* bufO0 = bufP + ND;                         // N*D: o0
    _Float16* h16   = bufO0 + ND;                        // N*D: GEMM out, [8][N][128]
    _Float16* y16   = h16 + ND;                          // N*D: agg out (pre-BN)
    _Float16* Wt3   = y16 + ND;                          // 3*D*D fp16 (W^T)
    // total ≈ 99 MB

    hipMemsetAsync(ideg, 0, N_NODES * sizeof(int), stream);
    hipMemsetAsync(pooled, 0, (size_t)NGRAPH * D_DIM * sizeof(float), stream);
    hipMemsetAsync(asrc, 0, (size_t)2 * N_NODES * H_HEADS * sizeof(float), stream);
    deg_kernel<<<(ETOT + 255) / 256, 256, 0, stream>>>(ei, ideg);
    scan_kernel<<<1, 256, 0, stream>>>(ideg, ioff);
    scatter_kernel<<<(ETOT + 255) / 256, 256, 0, stream>>>(ei, ioff, csr_src, csr_dst);
    xconv_kernel<<<(int)(ND / 4 + 255) / 256, 256, 0, stream>>>(x, bufP, (int)(ND / 4));
    wtconv_kernel<<<dim3(32, 32, 3), 256, 0, stream>>>(W, Wt3);

    // layer i: A = Ain[i]; prev = Pin[i] (all fp16); bn output -> Oout[i]
    const _Float16* Ain[3]  = {bufP, bufO0, bufP};
    const _Float16* Pin[3]  = {bufP, bufP, bufO0};
    _Float16* Oout[3]       = {bufO0, bufP, bufP};

    for (int i = 0; i < NBLK; ++i) {
        gemm_mfma_kernel<<<1280, 256, 0, stream>>>(
            Ain[i], Wt3 + (size_t)i * D_DIM * D_DIM, h16,
            att_src + i * H_HEADS * C_CH, att_dst + i * H_HEADS * C_CH,
            asrc, adst, stats, N_NODES);
        edge_exp_kernel<<<(ETOT + 255) / 256, 256, 0, stream>>>(csr_src, csr_dst,
                                                                asrc, adst, exw);
        agg_kernel<<<(N_NODES / 4) * H_HEADS, 256, 0, stream>>>(
            h16, exw, ioff, csr_src, Pin[i], att_bias + i * D_DIM, y16);
        bn_stats_kernel<<<256, 256, 0, stream>>>(y16, stats);
        bn_apply_kernel<<<(int)(ND / 8 + 255) / 256, 256, 0, stream>>>(
            y16, stats, gamma + i * D_DIM, beta + i * D_DIM, Oout[i], asrc);
    }

    pool_kernel<<<dim3(8, NGRAPH), 256, 0, stream>>>(bufP, batch, pooled);
    final_kernel<<<NGRAPH, 256, 0, stream>>>(pooled, batch, Wout, bout, out);
}

// Round 15
// 542.132 us; speedup vs baseline: 1.0495x; 1.0495x over previous
//
#include <hip/hip_runtime.h>
#include <hip/hip_bf16.h>

#define N_NODES 10000
#define E_EDGES 160000
#define ETOT    170000   // E + N self loops
#define H_HEADS 8
#define C_CH    128
#define D_DIM   1024
#define NBLK    3
#define NGRAPH  64
#define NEG_SLOPE 0.2f
#define BN_EPS  1e-5f

typedef __attribute__((ext_vector_type(8))) _Float16 half8;
typedef __attribute__((ext_vector_type(4))) _Float16 half4;
typedef __attribute__((ext_vector_type(2))) _Float16 half2v;
typedef __attribute__((ext_vector_type(4))) float f32x4;

// first index i in sorted batch[0..N) with batch[i] >= g
__device__ inline int lower_bound_batch(const int* __restrict__ batch, int g) {
    int lo = 0, hi = N_NODES;
    while (lo < hi) {
        int mid = (lo + hi) >> 1;
        if (batch[mid] < g) lo = mid + 1;
        else hi = mid;
    }
    return lo;
}

// ---------------- CSR build ----------------
__global__ void deg_kernel(const int* __restrict__ ei, int* __restrict__ deg) {
    int tid = blockIdx.x * blockDim.x + threadIdx.x;
    if (tid >= ETOT) return;
    int dst = (tid < E_EDGES) ? ei[E_EDGES + tid] : (tid - E_EDGES);
    atomicAdd(&deg[dst], 1);
}

__global__ void scan_kernel(const int* __restrict__ deg, int* __restrict__ ioff) {
    __shared__ int part[256];
    int t = threadIdx.x;
    const int CH = (N_NODES + 255) / 256; // 40
    int base = t * CH;
    int s = 0;
    for (int j = 0; j < CH; ++j) {
        int idx = base + j;
        if (idx < N_NODES) s += deg[idx];
    }
    part[t] = s;
    __syncthreads();
    for (int o = 1; o < 256; o <<= 1) {
        int v = 0;
        if (t >= o) v = part[t - o];
        __syncthreads();
        part[t] += v;
        __syncthreads();
    }
    int run = (t == 0) ? 0 : part[t - 1];
    for (int j = 0; j < CH; ++j) {
        int idx = base + j;
        if (idx < N_NODES) { ioff[idx] = run; run += deg[idx]; }
    }
}

__global__ void scatter_kernel(const int* __restrict__ ei, int* __restrict__ ioff,
                               int* __restrict__ csr_src, int* __restrict__ csr_dst) {
    int tid = blockIdx.x * blockDim.x + threadIdx.x;
    if (tid >= ETOT) return;
    int src, dst;
    if (tid < E_EDGES) { src = ei[tid]; dst = ei[E_EDGES + tid]; }
    else { src = dst = tid - E_EDGES; }
    int pos = atomicAdd(&ioff[dst], 1);
    csr_src[pos] = src;
    csr_dst[pos] = dst;
}

// ---------------- x -> fp16 ----------------
__global__ __launch_bounds__(256) void xconv_kernel(const float* __restrict__ in,
                                                    _Float16* __restrict__ o, int n4) {
    int i = blockIdx.x * blockDim.x + threadIdx.x;
    if (i >= n4) return;
    float4 v = ((const float4*)in)[i];
    half4 h = {(_Float16)v.x, (_Float16)v.y, (_Float16)v.z, (_Float16)v.w};
    ((half4*)o)[i] = h;
}

// W [k][n] fp32 -> Wt [n][k] fp16 (transposed); blockIdx.z = layer
__global__ __launch_bounds__(256) void wtconv_kernel(const float* __restrict__ Wall,
                                                     _Float16* __restrict__ t16all) {
    const float* W = Wall + (size_t)blockIdx.z * D_DIM * D_DIM;
    _Float16* t16 = t16all + (size_t)blockIdx.z * D_DIM * D_DIM;
    __shared__ float t[32][33];
    int bn = blockIdx.x * 32;
    int bk = blockIdx.y * 32;
    int tx = threadIdx.x & 31;
    int ty = threadIdx.x >> 5;
#pragma unroll
    for (int r = 0; r < 32; r += 8)
        t[ty + r][tx] = W[(size_t)(bk + ty + r) * D_DIM + bn + tx];
    __syncthreads();
#pragma unroll
    for (int r = 0; r < 32; r += 8)
        t16[(size_t)(bn + ty + r) * D_DIM + bk + tx] = (_Float16)t[tx][ty + r];
}

// ---------------- fp16 MFMA GEMM + fused attention-logit epilogue ----------------
// R9-proven shape (session best, 545.6us total): 128x64 tile, 4 waves,
// acc[2][4] = 32 AGPR -> 4 waves/SIMD, grid 79x16 work blocks, occupancy
// ~36%. The 2-barrier schedule's ~44us is this GEMM's structural floor
// (dbuf x3 regressed via occupancy loss; BK-doubling neutral; tile-halving
// neutral-negative). Att-logit partials via atomicAdd into pre-zeroed
// asrc/adst. R2-proven XOR swizzle. XCD map: c=bx&7 owns m-tiles {c,c+8,..}.
__global__ __launch_bounds__(256, 4) void gemm_mfma_kernel(const _Float16* __restrict__ A,
                                                           const _Float16* __restrict__ Bt,
                                                           _Float16* __restrict__ Hout,
                                                           const float* __restrict__ att_s,
                                                           const float* __restrict__ att_d,
                                                           float* __restrict__ asrc,
                                                           float* __restrict__ adst,
                                                           float* __restrict__ stats, int M) {
    __shared__ short As[128 * 64]; // [m][k] fp16 bits, swizzled slots, 16 KB
    __shared__ short Bs[64 * 64];  // [n][k], 8 KB
    int bx = blockIdx.x;
    int tid = threadIdx.x;
    if (bx == 0) {
#pragma unroll
        for (int j = 0; j < 8; ++j) stats[tid + j * 256] = 0.f;
    }
    int c = bx & 7;
    int nt = (bx >> 3) & 15;
    int mt = c + 8 * (bx >> 7);
    if (mt >= 79) return;
    int bm = mt * 128;
    int head = nt >> 1;
    int bncol = (nt & 1) * 64;   // col offset within head's 128 channels
    int bnrow = nt * 64;         // row offset in Bt [1024][1024]
    int wave = tid >> 6;
    int lane = tid & 63;
    int wm = wave * 32;          // wave owns rows wm..wm+31, all 64 cols
    int quad = lane >> 4;
    int l16 = lane & 15;

    f32x4 acc[2][4];
#pragma unroll
    for (int i = 0; i < 2; ++i)
#pragma unroll
        for (int j = 0; j < 4; ++j) acc[i][j] = (f32x4){0.f, 0.f, 0.f, 0.f};

    // staging geometry: 8 lanes/row, 8 x 16B slots per 128B row (BK=64)
    int srow8 = lane >> 3;                       // 0..7
    int sswz = ((lane & 7) ^ srow8) << 4;        // swizzled source slot (bytes)
    const char* gA[4];
    const char* gB[2];
    char* ldA[4];
    char* ldB[2];
#pragma unroll
    for (int r = 0; r < 4; ++r) {
        int arow = wave * 8 + r * 32 + srow8;    // 0..127
        int ga = bm + arow;
        if (ga > M - 1) ga = M - 1;
        gA[r] = (const char*)(A + (size_t)ga * 1024) + sswz;
        ldA[r] = (char*)As + (wave * 8 + r * 32) * 128;  // wave-uniform dest
    }
#pragma unroll
    for (int r = 0; r < 2; ++r) {
        int brow = wave * 8 + r * 32 + srow8;    // 0..63
        gB[r] = (const char*)(Bt + (size_t)(bnrow + brow) * 1024) + sswz;
        ldB[r] = (char*)Bs + (wave * 8 + r * 32) * 128;
    }

    int xr = l16 & 7;   // read-side XOR = row&7
    for (int kb = 0; kb < 16; ++kb) {
        int ko = kb * 128;  // 64 fp16 per row per step
#pragma unroll
        for (int r = 0; r < 4; ++r)
            __builtin_amdgcn_global_load_lds(
                (const __attribute__((address_space(1))) void*)(gA[r] + ko),
                (__attribute__((address_space(3))) void*)ldA[r], 16, 0, 0);
#pragma unroll
        for (int r = 0; r < 2; ++r)
            __builtin_amdgcn_global_load_lds(
                (const __attribute__((address_space(1))) void*)(gB[r] + ko),
                (__attribute__((address_space(3))) void*)ldB[r], 16, 0, 0);
        __syncthreads();
#pragma unroll
        for (int h = 0; h < 2; ++h) {
            int sl = (quad + h * 4) ^ xr;   // swizzled 16B slot to read
            half8 af[2], bfr[4];
#pragma unroll
            for (int i = 0; i < 2; ++i)
                af[i] = *(const half8*)(As + (wm + i * 16 + l16) * 64 + sl * 8);
#pragma unroll
            for (int j = 0; j < 4; ++j)
                bfr[j] = *(const half8*)(Bs + (j * 16 + l16) * 64 + sl * 8);
#pragma unroll
            for (int i = 0; i < 2; ++i)
#pragma unroll
                for (int j = 0; j < 4; ++j)
                    acc[i][j] = __builtin_amdgcn_mfma_f32_16x16x32_f16(af[i], bfr[j], acc[i][j], 0, 0, 0);
        }
        __syncthreads();
    }

    // attention-logit partial dots over this block's 64 cols; full 128-channel
    // dot is completed via atomicAdd across the nt-even/nt-odd block pair.
    float wsv[4], wdv[4];
#pragma unroll
    for (int j = 0; j < 4; ++j) {
        int cc = bncol + j * 16 + l16;
        wsv[j] = att_s[head * 128 + cc];
        wdv[j] = att_d[head * 128 + cc];
    }
#pragma unroll
    for (int i = 0; i < 2; ++i) {
#pragma unroll
        for (int reg = 0; reg < 4; ++reg) {
            float p = acc[i][0][reg] * wsv[0] + acc[i][1][reg] * wsv[1] +
                      acc[i][2][reg] * wsv[2] + acc[i][3][reg] * wsv[3];
            float q = acc[i][0][reg] * wdv[0] + acc[i][1][reg] * wdv[1] +
                      acc[i][2][reg] * wdv[2] + acc[i][3][reg] * wdv[3];
#pragma unroll
            for (int o = 1; o < 16; o <<= 1) {
                p += __shfl_xor(p, o);
                q += __shfl_xor(q, o);
            }
            if (l16 == 0) {
                int gr = bm + wm + i * 16 + quad * 4 + reg;
                if (gr < M) {
                    atomicAdd(&asrc[gr * 8 + head], p);
                    atomicAdd(&adst[gr * 8 + head], q);
                }
            }
        }
    }
    // store h fp16, head-major: Hout[head][row][col128]
#pragma unroll
    for (int i = 0; i < 2; ++i) {
#pragma unroll
        for (int reg = 0; reg < 4; ++reg) {
            int gr = bm + wm + i * 16 + quad * 4 + reg;
            if (gr < M) {
                _Float16* hp = Hout + (size_t)head * N_NODES * 128 + (size_t)gr * 128 + bncol + l16;
#pragma unroll
                for (int j = 0; j < 4; ++j) hp[j * 16] = (_Float16)acc[i][j][reg];
            }
        }
    }
}

// ---------------- per-edge softmax numerator pre-pass ----------------
// One thread per CSR slot, all 8 heads. Hoists exp(leaky(asrc[src]+adst[dst]))
// out of agg's channel-parallel inner loop (R0 lesson; R6's in-loop exp
// regressed). R21: exw is HEAD-MAJOR [8][ETOT] (R7 proven: agg FETCH
// 56.5 -> 28 MB, cross-XCD over-fetch eliminated).
__global__ __launch_bounds__(256) void edge_exp_kernel(const int* __restrict__ csr_src,
                                                       const int* __restrict__ csr_dst,
                                                       const float* __restrict__ asrc,
                                                       const float* __restrict__ adst,
                                                       float* __restrict__ exw) {
    int p = blockIdx.x * 256 + threadIdx.x;
    if (p >= ETOT) return;
    int s = csr_src[p];
    int d = csr_dst[p];
    float4 s0 = *(const float4*)(asrc + (unsigned)s * 8u);
    float4 s1 = *(const float4*)(asrc + (unsigned)s * 8u + 4u);
    float4 d0 = *(const float4*)(adst + (unsigned)d * 8u);
    float4 d1 = *(const float4*)(adst + (unsigned)d * 8u + 4u);
    float e[8] = {s0.x + d0.x, s0.y + d0.y, s0.z + d0.z, s0.w + d0.w,
                  s1.x + d1.x, s1.y + d1.y, s1.z + d1.z, s1.w + d1.w};
#pragma unroll
    for (int j = 0; j < 8; ++j) {
        float v = e[j];
        v = (v > 0.f) ? v : NEG_SLOPE * v;
        exw[j * ETOT + p] = __expf(v);
    }
}

// ---------------- fused edge-softmax aggregation v5 (R23, proven R9) ----------------
// One wave per (node,head): sub = lane>>4 is the edge slot (4 edges per
// gather instruction), l16 = lane&15 covers 128 ch via half8. Single loop
// bound per wave -> zero divergence. shfl_xor(16,32) folds the 4 slots;
// lanes 0-15 (sub==0) write the half8 row. head = bx&7 keeps per-XCD h16
// slice (2.56 MB) L2-resident.
__global__ __launch_bounds__(256) void agg_kernel(const _Float16* __restrict__ h16,
                                                  const float* __restrict__ exw,
                                                  const int* __restrict__ ioff,
                                                  const int* __restrict__ csr_src,
                                                  const _Float16* __restrict__ prevh,
                                                  const float* __restrict__ bias,
                                                  _Float16* __restrict__ yout) {
    int bx = blockIdx.x;
    int head = bx & 7;
    int wave = threadIdx.x >> 6;
    int lane = threadIdx.x & 63;
    int sub = lane >> 4;              // edge slot 0..3
    int l16 = lane & 15;              // channel group (8 ch each)
    unsigned c8 = (unsigned)(l16 * 8);
    int n = (bx >> 3) * 4 + wave;     // N=10000 divisible by 4
    const _Float16* hh = h16 + (size_t)head * N_NODES * 128;
    const float* exh = exw + (size_t)head * ETOT;
    int start = (n == 0) ? 0 : ioff[n - 1];
    int end = ioff[n];
    float den = 0.f;
    float acc[8];
#pragma unroll
    for (int j = 0; j < 8; ++j) acc[j] = 0.f;
    int p = start;
    for (; p + 8 <= end; p += 8) {
        int sA = csr_src[p + sub];
        int sB = csr_src[p + 4 + sub];
        float xA = exh[p + sub];
        float xB = exh[p + 4 + sub];
        half8 hA = *(const half8*)(hh + ((unsigned)sA * 128u + c8));
        half8 hB = *(const half8*)(hh + ((unsigned)sB * 128u + c8));
        den += xA + xB;
#pragma unroll
        for (int j = 0; j < 8; ++j)
            acc[j] = fmaf(xA, (float)hA[j], fmaf(xB, (float)hB[j], acc[j]));
    }
    for (; p + 4 <= end; p += 4) {
        int s = csr_src[p + sub];
        float x = exh[p + sub];
        half8 hv = *(const half8*)(hh + ((unsigned)s * 128u + c8));
        den += x;
#pragma unroll
        for (int j = 0; j < 8; ++j)
            acc[j] = fmaf(x, (float)hv[j], acc[j]);
    }
    if (p + sub < end) {
        int s = csr_src[p + sub];
        float x = exh[p + sub];
        half8 hv = *(const half8*)(hh + ((unsigned)s * 128u + c8));
        den += x;
#pragma unroll
        for (int j = 0; j < 8; ++j)
            acc[j] = fmaf(x, (float)hv[j], acc[j]);
    }
    // fold the 4 edge slots (lanes ^16, ^32)
#pragma unroll
    for (int j = 0; j < 8; ++j) {
        acc[j] += __shfl_xor(acc[j], 16);
        acc[j] += __shfl_xor(acc[j], 32);
    }
    den += __shfl_xor(den, 16);
    den += __shfl_xor(den, 32);
    if (sub == 0) {
        float invd = 1.0f / den;
        int col = head * 128 + l16 * 8;
        half8 ph = *(const half8*)(prevh + (size_t)n * 1024 + col);
        float4 b0 = *(const float4*)(bias + col);
        float4 b1 = *(const float4*)(bias + col + 4);
        half8 o;
        o[0] = (_Float16)fmaf(acc[0], invd, (float)ph[0] + b0.x);
        o[1] = (_Float16)fmaf(acc[1], invd, (float)ph[1] + b0.y);
        o[2] = (_Float16)fmaf(acc[2], invd, (float)ph[2] + b0.z);
        o[3] = (_Float16)fmaf(acc[3], invd, (float)ph[3] + b0.w);
        o[4] = (_Float16)fmaf(acc[4], invd, (float)ph[4] + b1.x);
        o[5] = (_Float16)fmaf(acc[5], invd, (float)ph[5] + b1.y);
        o[6] = (_Float16)fmaf(acc[6], invd, (float)ph[6] + b1.z);
        o[7] = (_Float16)fmaf(acc[7], invd, (float)ph[7] + b1.w);
        *(half8*)(yout + (size_t)n * 1024 + col) = o;
    }
}

// ---------------- batchnorm (fp16 y) ----------------
// R9-proven form (session best; R12's half8-array rewrite spilled to scratch
// at VGPR 16 -> 116us; R14's half4 form doubled atomic chains -> slower).
// Stats from the same fp16-rounded y16 that bn_apply reads (R11 lesson),
// 5000-row pre-reduction per atomic (R13 lesson). stats zeroed by gemm
// block 0.
__global__ void bn_stats_kernel(const _Float16* __restrict__ y, float* __restrict__ stats) {
    int col = (blockIdx.x * 256 + threadIdx.x) * 2;  // grid.x = 2
    float s0 = 0.f, s1 = 0.f, q0 = 0.f, q1 = 0.f;
    for (int r = blockIdx.y; r < N_NODES; r += gridDim.y) {
        half2v v = *(const half2v*)(y + (size_t)r * 1024 + col);
        float a = (float)v[0], b = (float)v[1];
        s0 += a; q0 += a * a;
        s1 += b; q1 += b * b;
    }
    atomicAdd(&stats[col], s0);
    atomicAdd(&stats[col + 1], s1);
    atomicAdd(&stats[1024 + col], q0);
    atomicAdd(&stats[1024 + col + 1], q1);
}

// normalize+relu: y16 -> o16 (o is next layer's GEMM A / prev / pool input).
// R9-proven form. Prefix threads also zero asrc/adst (2*N*H floats) for the
// NEXT layer's gemm atomics (edge_exp of this layer already consumed them —
// stream-ordered).
__global__ void bn_apply_kernel(const _Float16* __restrict__ y, const float* __restrict__ stats,
                                const float* __restrict__ gamma, const float* __restrict__ beta,
                                _Float16* __restrict__ oout, float* __restrict__ azero) {
    int idx4 = blockIdx.x * blockDim.x + threadIdx.x;
    if (idx4 < 2 * N_NODES * H_HEADS / 4)
        ((float4*)azero)[idx4] = make_float4(0.f, 0.f, 0.f, 0.f);
    if (idx4 >= N_NODES * D_DIM / 4) return;
    int base = idx4 * 4;
    int col = base & 1023;
    const float invN = 1.0f / (float)N_NODES;
    half4 v = ((const half4*)y)[idx4];
    float r[4];
#pragma unroll
    for (int j = 0; j < 4; ++j) {
        int cc = col + j;
        float mu = stats[cc] * invN;
        float var = stats[1024 + cc] * invN - mu * mu;
        float t = ((float)v[j] - mu) * rsqrtf(var + BN_EPS) * gamma[cc] + beta[cc];
        r[j] = fmaxf(t, 0.f);
    }
    half4 h = {(_Float16)r[0], (_Float16)r[1], (_Float16)r[2], (_Float16)r[3]};
    ((half4*)oout)[idx4] = h;
}

// ---------------- pooling stage 1: partial col-sums, 512 blocks ----------------
__global__ __launch_bounds__(256) void pool_kernel(const _Float16* __restrict__ h3,
                                                   const int* __restrict__ batch,
                                                   float* __restrict__ pooled) {
    int g = blockIdx.y;
    int col = threadIdx.x * 4;
    int lo = lower_bound_batch(batch, g);
    int hi = lower_bound_batch(batch, g + 1);
    int len = hi - lo;
    int r0 = lo + (int)(((long long)len * blockIdx.x) >> 3);
    int r1 = lo + (int)(((long long)len * (blockIdx.x + 1)) >> 3);
    float a0 = 0.f, a1 = 0.f, a2 = 0.f, a3 = 0.f;
    for (int r = r0; r < r1; ++r) {
        half4 v = *(const half4*)(h3 + (size_t)r * 1024 + col);
        a0 += (float)v[0]; a1 += (float)v[1]; a2 += (float)v[2]; a3 += (float)v[3];
    }
    if (r1 > r0) {
        atomicAdd(&pooled[(size_t)g * 1024 + col + 0], a0);
        atomicAdd(&pooled[(size_t)g * 1024 + col + 1], a1);
        atomicAdd(&pooled[(size_t)g * 1024 + col + 2], a2);
        atomicAdd(&pooled[(size_t)g * 1024 + col + 3], a3);
    }
}

__global__ void final_kernel(const float* __restrict__ pooled, const int* __restrict__ batch,
                             const float* __restrict__ Wout, const float* __restrict__ bout,
                             float* __restrict__ out) {
    int g = blockIdx.x;
    int t = threadIdx.x;
    float p0 = 0.f, p1 = 0.f;
    for (int d = t; d < 1024; d += 256) {
        float v = pooled[(size_t)g * 1024 + d];
        p0 = fmaf(v, Wout[2 * d], p0);
        p1 = fmaf(v, Wout[2 * d + 1], p1);
    }
    __shared__ float s0[256], s1[256];
    s0[t] = p0; s1[t] = p1;
    __syncthreads();
    for (int o = 128; o; o >>= 1) {
        if (t < o) { s0[t] += s0[t + o]; s1[t] += s1[t + o]; }
        __syncthreads();
    }
    if (t == 0) {
        int cnt = lower_bound_batch(batch, g + 1) - lower_bound_batch(batch, g);
        float inv = 1.0f / fmaxf((float)cnt, 1.0f);
        out[g * 2 + 0] = s0[0] * inv + bout[0];
        out[g * 2 + 1] = s1[0] * inv + bout[1];
    }
}

extern "C" void kernel_launch(void* const* d_in, const int* in_sizes, int n_in,
                              void* d_out, int out_size, void* d_ws, size_t ws_size,
                              hipStream_t stream) {
    const float* x        = (const float*)d_in[0];
    const int*   ei       = (const int*)d_in[1];
    const int*   batch    = (const int*)d_in[2];
    const float* W        = (const float*)d_in[3];
    const float* att_src  = (const float*)d_in[4];
    const float* att_dst  = (const float*)d_in[5];
    const float* att_bias = (const float*)d_in[6];
    const float* gamma    = (const float*)d_in[7];
    const float* beta     = (const float*)d_in[8];
    const float* Wout     = (const float*)d_in[9];
    const float* bout     = (const float*)d_in[10];
    float* out = (float*)d_out;

    const size_t ND = (size_t)N_NODES * D_DIM;
    float* ws = (float*)d_ws;
    float* asrc   = ws;                                  // N*H
    float* adst   = asrc + (size_t)N_NODES * H_HEADS;    // N*H (contiguous w/ asrc)
    float* stats  = adst + (size_t)N_NODES * H_HEADS;    // 2*D
    float* pooled = stats + 2 * D_DIM;                   // NG*D
    int* ideg     = (int*)(pooled + (size_t)NGRAPH * D_DIM); // N
    int* ioff     = ideg + N_NODES;                      // N
    int* csr_src  = ioff + N_NODES;                      // ETOT
    int* csr_dst  = csr_src + ETOT;                      // ETOT
    float* exw    = (float*)(csr_dst + ETOT);            // H*ETOT head-major (R21)
    _Float16* bufP  = (_Float16*)(exw + (size_t)ETOT * H_HEADS); // N*D: x16 -> o1 -> o2
    _Float16* bufO0 = bufP + ND;                         // N*D: o0
    _Float16* h16   = bufO0 + ND;                        // N*D: GEMM out, [8][N][128]
    _Float16* y16   = h16 + ND;                          // N*D: agg out (pre-BN)
    _Float16* Wt3   = y16 + ND;                          // 3*D*D fp16 (W^T)
    // total ≈ 99 MB

    hipMemsetAsync(ideg, 0, N_NODES * sizeof(int), stream);
    hipMemsetAsync(pooled, 0, (size_t)NGRAPH * D_DIM * sizeof(float), stream);
    hipMemsetAsync(asrc, 0, (size_t)2 * N_NODES * H_HEADS * sizeof(float), stream);
    deg_kernel<<<(ETOT + 255) / 256, 256, 0, stream>>>(ei, ideg);
    scan_kernel<<<1, 256, 0, stream>>>(ideg, ioff);
    scatter_kernel<<<(ETOT + 255) / 256, 256, 0, stream>>>(ei, ioff, csr_src, csr_dst);
    xconv_kernel<<<(int)(ND / 4 + 255) / 256, 256, 0, stream>>>(x, bufP, (int)(ND / 4));
    wtconv_kernel<<<dim3(32, 32, 3), 256, 0, stream>>>(W, Wt3);

    // layer i: A = Ain[i]; prev = Pin[i] (all fp16); bn output -> Oout[i]
    const _Float16* Ain[3]  = {bufP, bufO0, bufP};
    const _Float16* Pin[3]  = {bufP, bufP, bufO0};
    _Float16* Oout[3]       = {bufO0, bufP, bufP};

    for (int i = 0; i < NBLK; ++i) {
        gemm_mfma_kernel<<<1280, 256, 0, stream>>>(
            Ain[i], Wt3 + (size_t)i * D_DIM * D_DIM, h16,
            att_src + i * H_HEADS * C_CH, att_dst + i * H_HEADS * C_CH,
            asrc, adst, stats, N_NODES);
        edge_exp_kernel<<<(ETOT + 255) / 256, 256, 0, stream>>>(csr_src, csr_dst,
                                                                asrc, adst, exw);
        agg_kernel<<<(N_NODES / 4) * H_HEADS, 256, 0, stream>>>(
            h16, exw, ioff, csr_src, Pin[i], att_bias + i * D_DIM, y16);
        bn_stats_kernel<<<dim3(2, 128), 256, 0, stream>>>(y16, stats);
        bn_apply_kernel<<<(int)(ND / 4 + 255) / 256, 256, 0, stream>>>(
            y16, stats, gamma + i * D_DIM, beta + i * D_DIM, Oout[i], asrc);
    }

    pool_kernel<<<dim3(8, NGRAPH), 256, 0, stream>>>(bufP, batch, pooled);
    final_kernel<<<NGRAPH, 256, 0, stream>>>(pooled, batch, Wout, bout, out);
}